// Round 2
// 910.521 us; speedup vs baseline: 1.0386x; 1.0386x over previous
//
#include <hip/hip_runtime.h>
#include <stdint.h>

#define IN_CH 50
#define OUT_CH 121
#define OUT_PAD 128
#define LDS_STRIDE 136   // 128 + 8 bf16 pad -> row stride 272 B -> conflict-free b128 reads

typedef __attribute__((ext_vector_type(8))) __bf16 bf16x8;
typedef __attribute__((ext_vector_type(8))) short short8;
typedef __attribute__((ext_vector_type(4))) float f32x4;

__device__ __forceinline__ unsigned short f2bf(float f) {
  union { float f; unsigned int u; } v; v.f = f;
  unsigned int u = v.u;
  unsigned int r = u + 0x7fffu + ((u >> 16) & 1u);  // round-to-nearest-even
  return (unsigned short)(r >> 16);
}
__device__ __forceinline__ float bf2f(unsigned short b) {
  union { unsigned int u; float f; } v; v.u = ((unsigned int)b) << 16;
  return v.f;
}

// ---------------------------------------------------------------------------
// Kernel A: per-node first matmul. y[n][0:121] = bf16(x[n] @ W1), cols 121..127 = 0.
// ---------------------------------------------------------------------------
__global__ __launch_bounds__(128) void node_mlp1(
    const float* __restrict__ x, const float* __restrict__ W1,
    unsigned short* __restrict__ y, int Nn) {
  __shared__ float xs[8 * IN_CH];
  int nb = blockIdx.x * 8;
  int tid = threadIdx.x;
  for (int i = tid; i < 8 * IN_CH; i += 128) {
    int node = nb + i / IN_CH;
    xs[i] = (node < Nn) ? x[(size_t)nb * IN_CH + i] : 0.f;
  }
  __syncthreads();
  int c = tid;  // 0..127, output channel
  float acc[8];
#pragma unroll
  for (int n = 0; n < 8; ++n) acc[n] = 0.f;
  if (c < OUT_CH) {
    for (int k = 0; k < IN_CH; ++k) {
      float w = W1[k * OUT_CH + c];  // coalesced across threads
#pragma unroll
      for (int n = 0; n < 8; ++n) acc[n] += xs[n * IN_CH + k] * w;
    }
  }
#pragma unroll
  for (int n = 0; n < 8; ++n) {
    if (nb + n < Nn) {
      unsigned short v = (c < OUT_CH) ? f2bf(acc[n]) : (unsigned short)0;
      y[(size_t)(nb + n) * OUT_PAD + c] = v;
    }
  }
}

// ---------------------------------------------------------------------------
// Kernel W: W2^T as bf16, zero-padded to [128][128]. w2t[n*128+k] = bf16(W2[k][n]).
// ---------------------------------------------------------------------------
__global__ __launch_bounds__(256) void prep_w2(
    const float* __restrict__ W2, unsigned short* __restrict__ w2t) {
  int idx = blockIdx.x * 256 + threadIdx.x;  // 16384 total
  int n = idx >> 7, k = idx & 127;
  float v = (n < OUT_CH && k < OUT_CH) ? W2[k * OUT_CH + n] : 0.f;
  w2t[idx] = f2bf(v);
}

// ---------------------------------------------------------------------------
// combine + relu + bf16-pack for 8 consecutive channels (bit-identical to the
// original sH path: one_eps*a + b + b1, relu, RNE round).
// ---------------------------------------------------------------------------
__device__ __forceinline__ short8 combine8(const uint4& a, const uint4& b,
                                           const f32x4& bia, const f32x4& bib,
                                           float one_eps) {
  float bv[8] = {bia[0], bia[1], bia[2], bia[3], bib[0], bib[1], bib[2], bib[3]};
  unsigned int aw[4] = {a.x, a.y, a.z, a.w};
  unsigned int bw[4] = {b.x, b.y, b.z, b.w};
  union { short8 v; unsigned int w[4]; } u;
#pragma unroll
  for (int p = 0; p < 4; ++p) {
    float v0 = one_eps * bf2f((unsigned short)(aw[p] & 0xffffu)) +
               bf2f((unsigned short)(bw[p] & 0xffffu)) + bv[2 * p];
    float v1 = one_eps * bf2f((unsigned short)(aw[p] >> 16)) +
               bf2f((unsigned short)(bw[p] >> 16)) + bv[2 * p + 1];
    v0 = fmaxf(v0, 0.f);
    v1 = fmaxf(v1, 0.f);
    u.w[p] = (unsigned int)f2bf(v0) | ((unsigned int)f2bf(v1) << 16);
  }
  return u.v;
}

// ---------------------------------------------------------------------------
// Kernel B v2: 128 edges / 256-thread block (4 waves x 32 edges, 2 m-tiles).
//  - gather+combine directly into MFMA A fragments (no sH LDS round trip)
//  - B fragments reused across both m-tiles -> half the LDS B-read traffic
//  - nontemporal out stores to keep y resident in L2/L3
// ---------------------------------------------------------------------------
__global__ __launch_bounds__(256, 3) void edge_mlp2(
    const unsigned short* __restrict__ y,   // [N][128] bf16
    const int* __restrict__ eidx,           // [2][E] int32
    const uint4* __restrict__ w2t4,         // [2048] = [128][128] bf16
    const float* __restrict__ b1,
    const float* __restrict__ b2,
    const float* __restrict__ eps,
    float* __restrict__ out,
    int E) {
  __shared__ __align__(16) unsigned short sW[128 * LDS_STRIDE];  // 34816 B
  __shared__ __align__(16) float sB1[128];
  __shared__ float sB2[128];
  int tid = threadIdx.x;
  int lane = tid & 63;
  int wv = tid >> 6;
  int q = lane >> 4;    // quad within wave
  int l15 = lane & 15;  // A-row (edge) within 16-tile

  // edge indices for this lane's two m-tiles (issued early, resolved pre-barrier)
  int e0 = blockIdx.x * 128 + wv * 32 + l15;
  int r0 = __builtin_nontemporal_load(&eidx[e0]);
  int c0 = __builtin_nontemporal_load(&eidx[E + e0]);
  int r1 = __builtin_nontemporal_load(&eidx[e0 + 16]);
  int c1 = __builtin_nontemporal_load(&eidx[E + e0 + 16]);

  // stage W2^T into LDS (row stride 272 B)
  for (int cc = tid; cc < 2048; cc += 256) {
    int n = cc >> 4, k8 = (cc & 15) << 3;
    *((uint4*)&sW[n * LDS_STRIDE + k8]) = w2t4[cc];
  }
  if (tid < 128) {
    sB1[tid] = (tid < OUT_CH) ? b1[tid] : 0.f;
    sB2[tid] = (tid < OUT_CH) ? b2[tid] : 0.f;
  }
  __syncthreads();

  float one_eps = 1.0f + eps[0];

  // gather: each lane reads exactly the channels its A-fragments need
  // (4 lanes per row read 64 B contiguous per segment instruction)
  const uint4* yi0 = (const uint4*)(y + ((size_t)(unsigned)r0 << 7));
  const uint4* yj0 = (const uint4*)(y + ((size_t)(unsigned)c0 << 7));
  const uint4* yi1 = (const uint4*)(y + ((size_t)(unsigned)r1 << 7));
  const uint4* yj1 = (const uint4*)(y + ((size_t)(unsigned)c1 << 7));
  uint4 ga0[4], gb0[4], ga1[4], gb1[4];
#pragma unroll
  for (int ks = 0; ks < 4; ++ks) {
    int seg = q + ks * 4;   // channel offset q*8 + ks*32, in uint4 units
    ga0[ks] = yi0[seg]; gb0[ks] = yj0[seg];
    ga1[ks] = yi1[seg]; gb1[ks] = yj1[seg];
  }

  short8 afr[2][4];
#pragma unroll
  for (int ks = 0; ks < 4; ++ks) {
    f32x4 bia = *((const f32x4*)&sB1[q * 8 + ks * 32]);
    f32x4 bib = *((const f32x4*)&sB1[q * 8 + ks * 32 + 4]);
    afr[0][ks] = combine8(ga0[ks], gb0[ks], bia, bib, one_eps);
    afr[1][ks] = combine8(ga1[ks], gb1[ks], bia, bib, one_eps);
  }

  // MFMA: 2 m-tiles x 8 n-tiles x K=128. B fragments read once, used twice.
  f32x4 acc[2][8];
#pragma unroll
  for (int m = 0; m < 2; ++m)
#pragma unroll
    for (int nt = 0; nt < 8; ++nt) acc[m][nt] = (f32x4){0.f, 0.f, 0.f, 0.f};

#pragma unroll
  for (int nt = 0; nt < 8; ++nt) {
    short8 bfr[4];
#pragma unroll
    for (int ks = 0; ks < 4; ++ks)
      bfr[ks] = *(const short8*)&sW[(nt * 16 + l15) * LDS_STRIDE + q * 8 + ks * 32];
#pragma unroll
    for (int ks = 0; ks < 4; ++ks) {
      acc[0][nt] = __builtin_amdgcn_mfma_f32_16x16x32_bf16(
          __builtin_bit_cast(bf16x8, afr[0][ks]),
          __builtin_bit_cast(bf16x8, bfr[ks]), acc[0][nt], 0, 0, 0);
      acc[1][nt] = __builtin_amdgcn_mfma_f32_16x16x32_bf16(
          __builtin_bit_cast(bf16x8, afr[1][ks]),
          __builtin_bit_cast(bf16x8, bfr[ks]), acc[1][nt], 0, 0, 0);
    }
  }

  // Epilogue: two rounds (m = 0,1), out_s reuses sW. C/D layout: col=l15 (n),
  // row=q*4+rr (edge within 16-tile). Fully coalesced nontemporal fp32 stores.
  __syncthreads();  // all waves done reading sW
  float bb[8];
#pragma unroll
  for (int nt = 0; nt < 8; ++nt) bb[nt] = sB2[nt * 16 + l15];

  float* out_s = (float*)sW;  // 64*121*4 = 30976 B <= 34816 B
  size_t base = (size_t)blockIdx.x * 128 * OUT_CH;
#pragma unroll
  for (int m = 0; m < 2; ++m) {
    if (m) __syncthreads();  // previous round's reads of out_s are done
    int erow = wv * 16 + q * 4;
#pragma unroll
    for (int nt = 0; nt < 8; ++nt) {
      int n = nt * 16 + l15;
      if (n < OUT_CH) {
#pragma unroll
        for (int rr = 0; rr < 4; ++rr)
          out_s[(erow + rr) * OUT_CH + n] = acc[m][nt][rr] + bb[nt];
      }
    }
    __syncthreads();
    // compact row r (= wv*16 + q*4 + rr) maps to global edge
    //   blockIdx.x*128 + (r>>4)*32 + m*16 + (r&15)
    for (int g = 0; g < 4; ++g) {
      size_t dst = base + (size_t)((g * 32 + m * 16) * OUT_CH);
      const float* src = out_s + g * 16 * OUT_CH;
      for (int j = tid; j < 16 * OUT_CH; j += 256)
        __builtin_nontemporal_store(src[j], &out[dst + j]);
    }
  }
}

extern "C" void kernel_launch(void* const* d_in, const int* in_sizes, int n_in,
                              void* d_out, int out_size, void* d_ws, size_t ws_size,
                              hipStream_t stream) {
  const float* x      = (const float*)d_in[0];
  const int* ei       = (const int*)d_in[1];   // int64 in ref -> int32 in harness
  const float* W1     = (const float*)d_in[2];
  const float* b1     = (const float*)d_in[3];
  const float* W2     = (const float*)d_in[4];
  const float* b2     = (const float*)d_in[5];
  const float* eps    = (const float*)d_in[6];
  float* out          = (float*)d_out;

  int N = in_sizes[0] / IN_CH;            // 100000
  int E = in_sizes[1] / 2;                // 1600000

  unsigned short* y   = (unsigned short*)d_ws;              // N*128 bf16 = 25.6 MB
  unsigned short* w2t = y + (size_t)N * OUT_PAD;            // 128*128 bf16 = 32 KB

  node_mlp1<<<(N + 7) / 8, 128, 0, stream>>>(x, W1, y, N);
  prep_w2<<<64, 256, 0, stream>>>(W2, w2t);
  edge_mlp2<<<E / 128, 256, 0, stream>>>(y, ei, (const uint4*)w2t,
                                         b1, b2, eps, out, E);
}